// Round 6
// baseline (2265.905 us; speedup 1.0000x reference)
//
#include <hip/hip_runtime.h>
#include <stdint.h>

#define Vv 512
#define Ff 1024

typedef unsigned short u16;
typedef __attribute__((ext_vector_type(8))) short s16x8;
typedef __attribute__((ext_vector_type(4))) float f32x4;

// workspace layout (bytes)
#define OFF_WH   (0u)
#define OFF_WM   (2u << 20)
#define OFF_WL   (4u << 20)
#define OFF_A0   (6u << 20)
#define OFF_A1   (9u << 20)
#define OFF_CNT  (12u << 20)

// Exact 3-way bf16 truncation split: v == h + m + l (bit-exact, 24 mantissa bits)
__device__ __forceinline__ void split3(float v, u16& h, u16& m, u16& l) {
    unsigned u = __float_as_uint(v);
    float fh = __uint_as_float(u & 0xFFFF0000u);
    h = (u16)(u >> 16);
    float r1 = v - fh;                         // exact
    unsigned u1 = __float_as_uint(r1);
    float fm = __uint_as_float(u1 & 0xFFFF0000u);
    m = (u16)(u1 >> 16);
    float r2 = r1 - fm;                        // exact
    l = (u16)(__float_as_uint(r2) >> 16);
}

__device__ __forceinline__ float bf2f(short v) {
    return __uint_as_float(((unsigned)(u16)v) << 16);
}

// Fragment-major layouts (16B units):
//  A planes (512x1024, per lv 1MB): byte = ((i>>4)*32 + (j>>5))*1024 + (i&15)*64 + ((j>>3)&3)*16 + (j&7)*2
//  W planes (1024x1024, per lv 2MB): byte = ((j>>4)*32 + (k>>5))*1024 + (j&15)*64 + u4*16 + (k&7)*2
//    Wh/Wm: u4 = (k>>3)&3 (plain).  Wl: u4 = ((k>>3)&3) ^ (((j>>1)&3)&3) swizzled for LDS bank spread.

__global__ void wsplit_kernel(const float* __restrict__ W, char* __restrict__ ws) {
    int idx = blockIdx.x * 256 + threadIdx.x;   // 0..131071  (j x oct)
    int j = idx >> 7, oct = idx & 127;
    const float* wr = W + (size_t)j * Ff + oct * 8;
    s16x8 vh, vm, vl;
#pragma unroll
    for (int e = 0; e < 8; ++e) {
        u16 h, m, l; split3(wr[e], h, m, l);
        vh[e] = (short)h; vm[e] = (short)m; vl[e] = (short)l;
    }
    int jb = j >> 4, ob = oct >> 2, l15 = j & 15, l4 = oct & 3;
    unsigned tile = (unsigned)(jb * 32 + ob) * 1024u;
    unsigned up = tile + (unsigned)(l15 * 4 + l4) * 16u;
    unsigned us = tile + (unsigned)(l15 * 4 + (l4 ^ ((l15 >> 1) & 3))) * 16u;
    *(s16x8*)(ws + OFF_WH + up) = vh;
    *(s16x8*)(ws + OFF_WM + up) = vm;
    *(s16x8*)(ws + OFF_WL + us) = vl;
}

// t=0 state into A0 (fragment layout) + zero the barrier counters
__global__ void init_kernel(const float* __restrict__ X, const float* __restrict__ b,
                            char* __restrict__ ws) {
    int idx = blockIdx.x * 256 + threadIdx.x;   // 0..65535 (i x oct)
    if (idx < 512) ((unsigned*)(ws + OFF_CNT))[idx] = 0u;
    int i = idx >> 7, oct = idx & 127;
    s16x8 vh, vm, vl;
#pragma unroll
    for (int e = 0; e < 8; ++e) {
        int j = oct * 8 + e;
        float u = b[j];
        if (j < Vv && i != j) u = 0.5f * u + 0.5f * X[j];
        u = fmaxf(u, 0.f);
        u16 h, m, l; split3(u, h, m, l);
        vh[e] = (short)h; vm[e] = (short)m; vl[e] = (short)l;
    }
    unsigned byte = (unsigned)((i >> 4) * 32 + (oct >> 2)) * 1024u
                  + (unsigned)((i & 15) * 64 + (oct & 3) * 16);
    *(s16x8*)(ws + OFF_A0 + byte) = vh;
    *(s16x8*)(ws + OFF_A0 + (1u << 20) + byte) = vm;
    *(s16x8*)(ws + OFF_A0 + (2u << 20) + byte) = vl;
}

// Persistent megakernel: 256 blocks x 512 thr; block = (ig = 32-row group, js = 64-col slice).
// XCD mapping: ig pair <-> bid%8 so producers/consumers share an XCD L2.
// W-h/W-m: per-wave register fragments (loaded once). W-l: LDS-resident (loaded once).
// Per step: A fragments loaded straight to regs (dbuf), 24 MFMA/chunk/wave, kq-split over K.
__global__ __launch_bounds__(512, 2)
void mega_kernel(const float* __restrict__ X, const float* __restrict__ b,
                 char* __restrict__ ws) {
    extern __shared__ char smem[];   // 131072 (Wl) + 16384 (red) = 147456
    const int tid = threadIdx.x, bid = blockIdx.x;
    const int ig = (bid & 7) * 2 + (bid >> 7);
    const int js = (bid >> 3) & 15;
    const int lane = tid & 63, l15 = lane & 15, l4 = lane >> 4;
    const int w = tid >> 6, kq = w & 3, nh = w >> 2;

    const char* WhF = ws + OFF_WH;
    const char* WmF = ws + OFF_WM;
    const char* WlF = ws + OFF_WL;
    char* A0 = ws + OFF_A0;
    char* A1 = ws + OFF_A1;
    unsigned* cnt = (unsigned*)(ws + OFF_CNT);

    // ---- one-time: Wl (this block's 64-col slice) -> LDS, linear copy ----
    {
        const char* src = WlF + (size_t)js * (8192u * 16u);
#pragma unroll
        for (int q = 0; q < 16; ++q) {
            unsigned u = (unsigned)(q * 512 + tid) * 16u;
            __builtin_amdgcn_global_load_lds(
                (const __attribute__((address_space(1))) void*)(src + u),
                (__attribute__((address_space(3))) void*)(smem + u), 16, 0, 0);
        }
    }
    // ---- one-time: Wh/Wm fragments -> registers (128 VGPR) ----
    s16x8 Bh[8][2], Bm[8][2];
#pragma unroll
    for (int c = 0; c < 8; ++c)
#pragma unroll
        for (int nf = 0; nf < 2; ++nf) {
            unsigned byte = (unsigned)((js * 4 + nh * 2 + nf) * 32 + (c * 4 + kq)) * 1024u
                          + (unsigned)(l15 * 4 + l4) * 16u;
            Bh[c][nf] = *(const s16x8*)(WhF + byte);
            Bm[c][nf] = *(const s16x8*)(WmF + byte);
        }
    const int row = tid >> 4, col2 = (tid & 15) * 2;
    float bb[2][2];
#pragma unroll
    for (int p = 0; p < 2; ++p) {
        bb[p][0] = b[js * 64 + p * 32 + col2];
        bb[p][1] = b[js * 64 + p * 32 + col2 + 1];
    }
    const int i = ig * 32 + row;
    float* red = (float*)(smem + 131072);
    const unsigned aoffl = (unsigned)(l15 * 4 + l4) * 16u;
    const unsigned lswz = (unsigned)(l15 * 4 + (l4 ^ ((l15 >> 1) & 3))) * 16u;

    __syncthreads();   // Wl staged (drains vmcnt) + Whm regs ready

    for (int t = 1; t <= 126; ++t) {
        const char* srcA = (t & 1) ? A0 : A1;
        char* dstA = (t & 1) ? A1 : A0;

        f32x4 acc[2][2];
#pragma unroll
        for (int a = 0; a < 2; ++a)
#pragma unroll
            for (int c2 = 0; c2 < 2; ++c2) acc[a][c2] = (f32x4){0.f, 0.f, 0.f, 0.f};

        s16x8 Afr[2][3][2];
#define LOADA(pb, cc) do {                                                              \
        _Pragma("unroll")                                                               \
        for (int lv_ = 0; lv_ < 3; ++lv_)                                               \
            _Pragma("unroll")                                                           \
            for (int mf_ = 0; mf_ < 2; ++mf_)                                           \
                Afr[pb][lv_][mf_] = *(const s16x8*)(srcA + ((unsigned)lv_ << 20) +      \
                    (unsigned)(((ig * 2 + mf_) * 32 + (cc) * 4 + kq)) * 1024u + aoffl); \
    } while (0)
#define MM(acc_, a_, b_) asm("v_mfma_f32_16x16x32_bf16 %0, %1, %2, %0" : "+v"(acc_) : "v"(a_), "v"(b_))

        LOADA(0, 0);
#pragma unroll
        for (int c = 0; c < 8; ++c) {
            const int cur = c & 1;
            if (c < 7) LOADA(cur ^ 1, c + 1);
            s16x8 Bl[2];
#pragma unroll
            for (int nf = 0; nf < 2; ++nf) {
                unsigned lb = (unsigned)((nh * 2 + nf) * 32 + c * 4 + kq) * 1024u + lswz;
                Bl[nf] = *(const s16x8*)(smem + lb);
            }
            // 6 exact products: hh, hm, mh, hl, lh, mm  (4-chain interleave)
#pragma unroll
            for (int mf = 0; mf < 2; ++mf)
#pragma unroll
                for (int nf = 0; nf < 2; ++nf) MM(acc[mf][nf], Afr[cur][0][mf], Bh[c][nf]);
#pragma unroll
            for (int mf = 0; mf < 2; ++mf)
#pragma unroll
                for (int nf = 0; nf < 2; ++nf) MM(acc[mf][nf], Afr[cur][0][mf], Bm[c][nf]);
#pragma unroll
            for (int mf = 0; mf < 2; ++mf)
#pragma unroll
                for (int nf = 0; nf < 2; ++nf) MM(acc[mf][nf], Afr[cur][1][mf], Bh[c][nf]);
#pragma unroll
            for (int mf = 0; mf < 2; ++mf)
#pragma unroll
                for (int nf = 0; nf < 2; ++nf) MM(acc[mf][nf], Afr[cur][0][mf], Bl[nf]);
#pragma unroll
            for (int mf = 0; mf < 2; ++mf)
#pragma unroll
                for (int nf = 0; nf < 2; ++nf) MM(acc[mf][nf], Afr[cur][2][mf], Bh[c][nf]);
#pragma unroll
            for (int mf = 0; mf < 2; ++mf)
#pragma unroll
                for (int nf = 0; nf < 2; ++nf) MM(acc[mf][nf], Afr[cur][1][mf], Bm[c][nf]);
        }
        asm volatile("s_nop 7\n\ts_nop 7");   // MFMA->VALU hazard guard

        // ---- kq-reduction + epilogue, two nh passes over 16 KB red ----
        const float* xt = X + (size_t)t * Vv;
#pragma unroll
        for (int p = 0; p < 2; ++p) {
            if (nh == p) {
#pragma unroll
                for (int mf = 0; mf < 2; ++mf)
#pragma unroll
                    for (int nf = 0; nf < 2; ++nf)
#pragma unroll
                        for (int r = 0; r < 4; ++r) {
                            int rr = mf * 16 + l4 * 4 + r;   // C: col=lane&15, row=(lane>>4)*4+reg
                            int cc = nf * 16 + l15;
                            red[(kq * 32 + rr) * 32 + cc] = acc[mf][nf][r];
                        }
            }
            __syncthreads();
            {
                int jg0 = js * 64 + p * 32 + col2;
                float s0 = red[(0 + row) * 32 + col2]       + red[(32 + row) * 32 + col2]
                         + red[(64 + row) * 32 + col2]      + red[(96 + row) * 32 + col2];
                float s1 = red[(0 + row) * 32 + col2 + 1]   + red[(32 + row) * 32 + col2 + 1]
                         + red[(64 + row) * 32 + col2 + 1]  + red[(96 + row) * 32 + col2 + 1];
                float u0 = s0 + bb[p][0], u1 = s1 + bb[p][1];
                if (js < 8) {
                    float x0 = xt[jg0], x1 = xt[jg0 + 1];
                    if (i != jg0)     u0 = 0.5f * u0 + 0.5f * x0;
                    if (i != jg0 + 1) u1 = 0.5f * u1 + 0.5f * x1;
                }
                u0 = fmaxf(u0, 0.f); u1 = fmaxf(u1, 0.f);
                u16 h0, m0, l0, h1, m1, l1;
                split3(u0, h0, m0, l0); split3(u1, h1, m1, l1);
                unsigned byte = (unsigned)((ig * 2 + (row >> 4)) * 32 + js * 2 + p) * 1024u
                              + (unsigned)((i & 15) * 64 + ((col2 >> 3) & 3) * 16 + (col2 & 7) * 2);
                *(unsigned*)(dstA + byte) = (unsigned)h0 | ((unsigned)h1 << 16);
                *(unsigned*)(dstA + (1u << 20) + byte) = (unsigned)m0 | ((unsigned)m1 << 16);
                *(unsigned*)(dstA + (2u << 20) + byte) = (unsigned)l0 | ((unsigned)l1 << 16);
            }
            __syncthreads();
        }

        // ---- inter-block barrier among the 16 blocks sharing ig ----
        if (tid == 0) {
            __threadfence();                       // release: drain + make O visible device-wide
            atomicAdd(&cnt[ig * 32], 1u);
            unsigned goal = 16u * (unsigned)t;
            while (__hip_atomic_load(&cnt[ig * 32], __ATOMIC_RELAXED,
                                     __HIP_MEMORY_SCOPE_AGENT) < goal) {
                __builtin_amdgcn_s_sleep(2);
            }
            __threadfence();                       // acquire: invalidate stale caches
        }
        __syncthreads();
#undef LOADA
#undef MM
    }
}

// Final: out[i] = dot(R126[i,:], W[i,:]) + b[i]; R126 in A0 fragment layout (h+m+l exact).
__global__ void diag_kernel(const char* __restrict__ ws, const float* __restrict__ W,
                            const float* __restrict__ b, float* __restrict__ out) {
    int i = blockIdx.x, lane = threadIdx.x;
    const char* A0 = ws + OFF_A0;
    float s = 0.f;
#pragma unroll
    for (int rep = 0; rep < 2; ++rep) {
        int oct = lane + rep * 64;
        unsigned byte = (unsigned)((i >> 4) * 32 + (oct >> 2)) * 1024u
                      + (unsigned)((i & 15) * 64 + (oct & 3) * 16);
        s16x8 vh = *(const s16x8*)(A0 + byte);
        s16x8 vm = *(const s16x8*)(A0 + (1u << 20) + byte);
        s16x8 vl = *(const s16x8*)(A0 + (2u << 20) + byte);
        const float* wr = W + (size_t)i * Ff + oct * 8;
#pragma unroll
        for (int e = 0; e < 8; ++e) {
            float r = bf2f(vh[e]) + bf2f(vm[e]) + bf2f(vl[e]);
            s += r * wr[e];
        }
    }
#pragma unroll
    for (int off = 32; off > 0; off >>= 1) s += __shfl_down(s, off);
    if (lane == 0) out[i] = s + b[i];
}

extern "C" void kernel_launch(void* const* d_in, const int* in_sizes, int n_in,
                              void* d_out, int out_size, void* d_ws, size_t ws_size,
                              hipStream_t stream) {
    const float* X = (const float*)d_in[0];   // (128, 512)
    const float* W = (const float*)d_in[1];   // (1024, 1024)
    const float* b = (const float*)d_in[2];   // (1024,)
    float* out = (float*)d_out;
    char* ws = (char*)d_ws;

    static bool attr_set = false;
    hipFuncSetAttribute(reinterpret_cast<const void*>(mega_kernel),
                        hipFuncAttributeMaxDynamicSharedMemorySize, 147456);
    (void)attr_set;

    wsplit_kernel<<<512, 256, 0, stream>>>(W, ws);
    init_kernel<<<256, 256, 0, stream>>>(X, b, ws);
    mega_kernel<<<256, 512, 147456, stream>>>(X, b, ws);
    diag_kernel<<<512, 64, 0, stream>>>(ws, W, b, out);
}

// Round 7
// 1233.341 us; speedup vs baseline: 1.8372x; 1.8372x over previous
//
#include <hip/hip_runtime.h>
#include <stdint.h>

#define Vv 512
#define Ff 1024

typedef unsigned short u16;
typedef unsigned long long u64;
typedef __attribute__((ext_vector_type(8))) short s16x8;
typedef __attribute__((ext_vector_type(4))) float f32x4;

// workspace layout (bytes)
#define OFF_WH  (0ull)
#define OFF_WM  (2ull << 20)
#define OFF_WL  (4ull << 20)
#define OFF_A0  (6ull << 20)
#define OFF_A1  (9ull << 20)
#define OFF_FLG (12ull << 20)

// A buffer layout: 256 tiles (ig 16 x js 16), tile = 12288 B contiguous:
//   [lv 3][o 8][r 32] 16B units; element (i = ig*32+r, j = js*64+o*8+e) at
//   tile*12288 + lv*4096 + (o*32+r)*16 + e*2.  Producer (ig,js) writes its tile;
//   consumer (ig,*) chunk c IS tile (ig,c) -> linear copy to LDS.

// Exact 3-way bf16 truncation split: v == h + m + l (bit-exact, 24 mantissa bits)
__device__ __forceinline__ void split3(float v, u16& h, u16& m, u16& l) {
    unsigned u = __float_as_uint(v);
    float fh = __uint_as_float(u & 0xFFFF0000u);
    h = (u16)(u >> 16);
    float r1 = v - fh;                         // exact
    unsigned u1 = __float_as_uint(r1);
    float fm = __uint_as_float(u1 & 0xFFFF0000u);
    m = (u16)(u1 >> 16);
    float r2 = r1 - fm;                        // exact
    l = (u16)(__float_as_uint(r2) >> 16);
}

__device__ __forceinline__ float bf2f(short v) {
    return __uint_as_float(((unsigned)(u16)v) << 16);
}

// W planes. Wh/Wm frag-major: unit = (((js*4+nq)*16+c)*2+kh)*64 + o*16 + col
// (j = js*64+nq*16+col, k = c*64+kh*32+o*8+e).  Wl (per js-block 8192 units,
// LDS-linear): unit = js*8192 + (c*2+kh)*256 + o*64 + nq*16 + col.
__global__ void wsplit_kernel(const float* __restrict__ W, char* __restrict__ ws) {
    int idx = blockIdx.x * 256 + threadIdx.x;   // 0..131071 (j x k-octet)
    int j = idx >> 7, ko = idx & 127;
    const float* wr = W + (size_t)j * Ff + ko * 8;
    s16x8 vh, vm, vl;
#pragma unroll
    for (int e = 0; e < 8; ++e) {
        u16 h, m, l; split3(wr[e], h, m, l);
        vh[e] = (short)h; vm[e] = (short)m; vl[e] = (short)l;
    }
    int js = j >> 6, nq = (j >> 4) & 3, col = j & 15;
    int c = ko >> 3, kh = (ko >> 2) & 1, o = ko & 3;
    unsigned uhm = (unsigned)((((js * 4 + nq) * 16 + c) * 2 + kh) * 64 + o * 16 + col);
    unsigned ul  = (unsigned)(js * 8192 + (c * 2 + kh) * 256 + o * 64 + nq * 16 + col);
    *(s16x8*)(ws + OFF_WH + (size_t)uhm * 16) = vh;
    *(s16x8*)(ws + OFF_WM + (size_t)uhm * 16) = vm;
    *(s16x8*)(ws + OFF_WL + (size_t)ul * 16)  = vl;
}

// t=0 state into A0 tiles + zero the 256 tile flags
__global__ void init_kernel(const float* __restrict__ X, const float* __restrict__ b,
                            char* __restrict__ ws) {
    int idx = blockIdx.x * 256 + threadIdx.x;   // 0..65535 (i x j-octet)
    if (idx < 256) ((unsigned*)(ws + OFF_FLG))[idx] = 0u;
    int i = idx >> 7, jo = idx & 127;
    s16x8 vh, vm, vl;
#pragma unroll
    for (int e = 0; e < 8; ++e) {
        int j = jo * 8 + e;
        float u = b[j];
        if (j < Vv && i != j) u = 0.5f * u + 0.5f * X[j];
        u = fmaxf(u, 0.f);
        u16 h, m, l; split3(u, h, m, l);
        vh[e] = (short)h; vm[e] = (short)m; vl[e] = (short)l;
    }
    int ig = i >> 5, r = i & 31, js = jo >> 3, o = jo & 7;
    size_t tb = (size_t)(ig * 16 + js) * 12288 + (size_t)(o * 32 + r) * 16;
    *(s16x8*)(ws + OFF_A0 + tb)        = vh;
    *(s16x8*)(ws + OFF_A0 + tb + 4096) = vm;
    *(s16x8*)(ws + OFF_A0 + tb + 8192) = vl;
}

#define GLD(dst, addr) \
    asm volatile("global_load_dwordx2 %0, %1, off sc0 sc1" \
                 : "=v"(dst) : "v"((const void*)(addr)) : "memory")
#define GST(addr, val) \
    asm volatile("global_store_dwordx2 %0, %1, off sc0 sc1" \
                 :: "v"((void*)(addr)), "v"(val) : "memory")
#define MM(acc_, a_, b_) \
    asm("v_mfma_f32_16x16x32_bf16 %0, %1, %2, %0" : "+v"(acc_) : "v"(a_), "v"(b_))

// Persistent: 256 blocks x 512 thr; block = (ig row-group, js 64-col slice).
// 8 waves: kh = w&1 (K-half of 64-chunk), nq = w>>1 (16-col group).
// Wh/Wm in regs (128 VGPR), Wl in LDS (128 KB), A chunks dbuf'd (2x12 KB).
__global__ __launch_bounds__(512, 2)
void mega_kernel(const float* __restrict__ X, const float* __restrict__ b,
                 char* __restrict__ ws) {
    extern __shared__ char smem[];   // Wl 131072 | A slots 2x12288 (red reuses)
    const int tid = threadIdx.x, bid = blockIdx.x;
    const int ig = bid >> 4, js = bid & 15;
    const int lane = tid & 63, l15 = lane & 15, l4 = lane >> 4;
    const int w = tid >> 6, kh = w & 1, nq = w >> 1;

    unsigned* flg = (unsigned*)(ws + OFF_FLG);

    // one-time: Wl 64-col slice -> LDS (linear)
    {
        const char* src = ws + OFF_WL + (size_t)js * 131072;
#pragma unroll
        for (int q = 0; q < 16; ++q) {
            unsigned u = (unsigned)(q * 512 + tid) * 16u;
            __builtin_amdgcn_global_load_lds(
                (const __attribute__((address_space(1))) void*)(src + u),
                (__attribute__((address_space(3))) void*)(smem + u), 16, 0, 0);
        }
    }
    // one-time: Wh/Wm fragments -> registers
    s16x8 Bh[16], Bm[16];
#pragma unroll
    for (int c = 0; c < 16; ++c) {
        size_t ub = (size_t)((((js * 4 + nq) * 16 + c) * 2 + kh) * 64 + l4 * 16 + l15) * 16;
        Bh[c] = *(const s16x8*)(ws + OFF_WH + ub);
        Bm[c] = *(const s16x8*)(ws + OFF_WM + ub);
    }
    const int row = tid >> 4, c4 = (tid & 15) * 4;
    const int i_glob = ig * 32 + row;
    float bb[4];
#pragma unroll
    for (int e = 0; e < 4; ++e) bb[e] = b[js * 64 + c4 + e];
    float* red = (float*)(smem + 131072);

    __syncthreads();   // Wl staged (barrier drains vmcnt)

    for (int t = 1; t <= 126; ++t) {
        char* srcA = ws + ((t & 1) ? OFF_A0 : OFF_A1);
        char* dstA = ws + ((t & 1) ? OFF_A1 : OFF_A0);

        // parallel poll: lanes 0..15 of wave 0 wait all 16 producer tiles >= t-1
        if (tid < 16) {
            while ((int)__hip_atomic_load(&flg[ig * 16 + tid], __ATOMIC_RELAXED,
                                          __HIP_MEMORY_SCOPE_AGENT) < t - 1)
                __builtin_amdgcn_s_sleep(1);
        }
        __syncthreads();
        asm volatile("" ::: "memory");

        const char* tb = srcA + (size_t)ig * 16 * 12288;
        u64 g0[3], g1[3];
#pragma unroll
        for (int j2 = 0; j2 < 3; ++j2) GLD(g0[j2], tb + (size_t)tid * 8 + j2 * 4096);
        asm volatile("s_waitcnt vmcnt(0)" ::: "memory");
#pragma unroll
        for (int j2 = 0; j2 < 3; ++j2)
            *(u64*)(smem + 131072 + (size_t)tid * 8 + j2 * 4096) = g0[j2];
#pragma unroll
        for (int j2 = 0; j2 < 3; ++j2) GLD(g1[j2], tb + 12288 + (size_t)tid * 8 + j2 * 4096);
        __syncthreads();

        f32x4 acc[2];
        acc[0] = (f32x4){0.f, 0.f, 0.f, 0.f};
        acc[1] = (f32x4){0.f, 0.f, 0.f, 0.f};

#pragma unroll
        for (int c = 0; c < 16; ++c) {
            if (c + 2 < 16) {   // issue 2-ahead (flags for all chunks already verified)
                if (c & 1) {
#pragma unroll
                    for (int j2 = 0; j2 < 3; ++j2)
                        GLD(g1[j2], tb + (size_t)(c + 2) * 12288 + (size_t)tid * 8 + j2 * 4096);
                } else {
#pragma unroll
                    for (int j2 = 0; j2 < 3; ++j2)
                        GLD(g0[j2], tb + (size_t)(c + 2) * 12288 + (size_t)tid * 8 + j2 * 4096);
                }
            }
            const char* sb = smem + 131072 + (c & 1) * 12288;
            s16x8 Af[3][2];
#pragma unroll
            for (int lv = 0; lv < 3; ++lv)
#pragma unroll
                for (int mf = 0; mf < 2; ++mf)
                    Af[lv][mf] = *(const s16x8*)(sb +
                        (size_t)(lv * 256 + (kh * 4 + l4) * 32 + mf * 16 + l15) * 16);
            s16x8 Bl = *(const s16x8*)(smem +
                        (size_t)((c * 2 + kh) * 256 + l4 * 64 + nq * 16 + l15) * 16);

            MM(acc[0], Af[0][0], Bh[c]); MM(acc[1], Af[0][1], Bh[c]);   // hh
            MM(acc[0], Af[0][0], Bm[c]); MM(acc[1], Af[0][1], Bm[c]);   // hm
            MM(acc[0], Af[1][0], Bh[c]); MM(acc[1], Af[1][1], Bh[c]);   // mh
            MM(acc[0], Af[0][0], Bl);    MM(acc[1], Af[0][1], Bl);      // hl
            MM(acc[0], Af[2][0], Bh[c]); MM(acc[1], Af[2][1], Bh[c]);   // lh
            MM(acc[0], Af[1][0], Bm[c]); MM(acc[1], Af[1][1], Bm[c]);   // mm

            if (c < 15) {
                if (c + 2 < 16) asm volatile("s_waitcnt vmcnt(3)" ::: "memory");
                else            asm volatile("s_waitcnt vmcnt(0)" ::: "memory");
                char* wbuf = smem + 131072 + ((c + 1) & 1) * 12288;
                const u64* sg = (c & 1) ? g0 : g1;
#pragma unroll
                for (int j2 = 0; j2 < 3; ++j2)
                    *(u64*)(wbuf + (size_t)tid * 8 + j2 * 4096) = sg[j2];
            }
            __syncthreads();
        }

        asm volatile("s_nop 7\n\ts_nop 7");   // MFMA->VALU/LDS hazard guard

        // kh-pair reduction through LDS (red reuses A-slot area)
#pragma unroll
        for (int mf = 0; mf < 2; ++mf)
#pragma unroll
            for (int r = 0; r < 4; ++r)
                red[w * 512 + (mf * 16 + l4 * 4 + r) * 16 + l15] = acc[mf][r];
        __syncthreads();

        // epilogue: 4 outputs/thread
        {
            const int nqo = c4 >> 4, cl0 = c4 & 15;
            float4 p0 = *(const float4*)&red[(nqo * 2 + 0) * 512 + row * 16 + cl0];
            float4 p1 = *(const float4*)&red[(nqo * 2 + 1) * 512 + row * 16 + cl0];
            float s[4] = {p0.x + p1.x, p0.y + p1.y, p0.z + p1.z, p0.w + p1.w};
            const float* xt = X + (size_t)t * Vv;
            u64 ph = 0, pm = 0, pl = 0;
#pragma unroll
            for (int e = 0; e < 4; ++e) {
                int j = js * 64 + c4 + e;
                float u = s[e] + bb[e];
                if (js < 8 && i_glob != j) u = 0.5f * u + 0.5f * xt[j];
                u = fmaxf(u, 0.f);
                u16 h, m, l; split3(u, h, m, l);
                ph |= (u64)h << (e * 16);
                pm |= (u64)m << (e * 16);
                pl |= (u64)l << (e * 16);
            }
            size_t tbo = (size_t)(ig * 16 + js) * 12288
                       + (size_t)((c4 >> 3) * 32 + row) * 16 + (c4 & 7) * 2;
            GST(dstA + tbo, ph);
            GST(dstA + tbo + 4096, pm);
            GST(dstA + tbo + 8192, pl);
        }
        asm volatile("s_waitcnt vmcnt(0)" ::: "memory");
        __syncthreads();   // all waves' coherent stores drained
        if (tid == 0)
            __hip_atomic_store(&flg[ig * 16 + js], (unsigned)t, __ATOMIC_RELAXED,
                               __HIP_MEMORY_SCOPE_AGENT);
    }
}

// Final: out[i] = dot(R126[i,:], W[i,:]) + b[i]; R126 in A0 tiles (h+m+l exact)
__global__ void diag_kernel(const char* __restrict__ ws, const float* __restrict__ W,
                            const float* __restrict__ b, float* __restrict__ out) {
    int i = blockIdx.x, lane = threadIdx.x;
    const char* A0 = ws + OFF_A0;
    float s = 0.f;
#pragma unroll
    for (int rep = 0; rep < 2; ++rep) {
        int ko = lane + rep * 64;                 // k-octet 0..127
        int js = ko >> 3, o = ko & 7;
        size_t tb = (size_t)((i >> 5) * 16 + js) * 12288
                  + (size_t)(o * 32 + (i & 31)) * 16;
        s16x8 vh = *(const s16x8*)(A0 + tb);
        s16x8 vm = *(const s16x8*)(A0 + tb + 4096);
        s16x8 vl = *(const s16x8*)(A0 + tb + 8192);
        const float* wr = W + (size_t)i * Ff + ko * 8;
#pragma unroll
        for (int e = 0; e < 8; ++e)
            s += (bf2f(vh[e]) + bf2f(vm[e]) + bf2f(vl[e])) * wr[e];
    }
#pragma unroll
    for (int off = 32; off > 0; off >>= 1) s += __shfl_down(s, off);
    if (lane == 0) out[i] = s + b[i];
}

extern "C" void kernel_launch(void* const* d_in, const int* in_sizes, int n_in,
                              void* d_out, int out_size, void* d_ws, size_t ws_size,
                              hipStream_t stream) {
    const float* X = (const float*)d_in[0];   // (128, 512)
    const float* W = (const float*)d_in[1];   // (1024, 1024)
    const float* b = (const float*)d_in[2];   // (1024,)
    float* out = (float*)d_out;
    char* ws = (char*)d_ws;

    hipFuncSetAttribute(reinterpret_cast<const void*>(mega_kernel),
                        hipFuncAttributeMaxDynamicSharedMemorySize, 155648);

    wsplit_kernel<<<512, 256, 0, stream>>>(W, ws);
    init_kernel<<<256, 256, 0, stream>>>(X, b, ws);
    mega_kernel<<<256, 512, 155648, stream>>>(X, b, ws);
    diag_kernel<<<512, 64, 0, stream>>>(ws, W, b, out);
}

// Round 8
// 1146.470 us; speedup vs baseline: 1.9764x; 1.0758x over previous
//
#include <hip/hip_runtime.h>
#include <stdint.h>

#define Vv 512
#define Ff 1024

typedef unsigned short u16;
typedef unsigned long long u64;
typedef __attribute__((ext_vector_type(8))) short s16x8;
typedef __attribute__((ext_vector_type(4))) float f32x4;

// workspace layout (bytes)
#define OFF_WH  (0ull)
#define OFF_WM  (2ull << 20)
#define OFF_WL  (4ull << 20)
#define OFF_A0  (6ull << 20)
#define OFF_A1  (9ull << 20)
#define OFF_FLG (12ull << 20)

// A buffer: 256 tiles (ig 16 x js 16), tile = 12288 B: [lv 3][o 8][r 32] 16B units;
// element (i=ig*32+r, j=js*64+o*8+e) at tile*12288 + lv*4096 + (o*32+r)*16 + e*2.

// Exact 3-way bf16 truncation split: v == h + m + l (bit-exact, 24 mantissa bits)
__device__ __forceinline__ void split3(float v, u16& h, u16& m, u16& l) {
    unsigned u = __float_as_uint(v);
    float fh = __uint_as_float(u & 0xFFFF0000u);
    h = (u16)(u >> 16);
    float r1 = v - fh;                         // exact
    unsigned u1 = __float_as_uint(r1);
    float fm = __uint_as_float(u1 & 0xFFFF0000u);
    m = (u16)(u1 >> 16);
    float r2 = r1 - fm;                        // exact
    l = (u16)(__float_as_uint(r2) >> 16);
}

__device__ __forceinline__ float bf2f(short v) {
    return __uint_as_float(((unsigned)(u16)v) << 16);
}

// W planes. Wh/Wm frag-major: unit = (((js*4+nq)*16+c)*2+kh)*64 + o*16 + col.
// Wl (per js-block 8192 units, LDS-linear): unit = js*8192 + (c*2+kh)*256 + o*64 + nq*16 + col.
__global__ void wsplit_kernel(const float* __restrict__ W, char* __restrict__ ws) {
    int idx = blockIdx.x * 256 + threadIdx.x;   // 0..131071 (j x k-octet)
    int j = idx >> 7, ko = idx & 127;
    const float* wr = W + (size_t)j * Ff + ko * 8;
    s16x8 vh, vm, vl;
#pragma unroll
    for (int e = 0; e < 8; ++e) {
        u16 h, m, l; split3(wr[e], h, m, l);
        vh[e] = (short)h; vm[e] = (short)m; vl[e] = (short)l;
    }
    int js = j >> 6, nq = (j >> 4) & 3, col = j & 15;
    int c = ko >> 3, kh = (ko >> 2) & 1, o = ko & 3;
    unsigned uhm = (unsigned)((((js * 4 + nq) * 16 + c) * 2 + kh) * 64 + o * 16 + col);
    unsigned ul  = (unsigned)(js * 8192 + (c * 2 + kh) * 256 + o * 64 + nq * 16 + col);
    *(s16x8*)(ws + OFF_WH + (size_t)uhm * 16) = vh;
    *(s16x8*)(ws + OFF_WM + (size_t)uhm * 16) = vm;
    *(s16x8*)(ws + OFF_WL + (size_t)ul * 16)  = vl;
}

// t=0 state into A0 tiles + zero the 256 tile flags
__global__ void init_kernel(const float* __restrict__ X, const float* __restrict__ b,
                            char* __restrict__ ws) {
    int idx = blockIdx.x * 256 + threadIdx.x;   // 0..65535 (i x j-octet)
    if (idx < 256) ((unsigned*)(ws + OFF_FLG))[idx] = 0u;
    int i = idx >> 7, jo = idx & 127;
    s16x8 vh, vm, vl;
#pragma unroll
    for (int e = 0; e < 8; ++e) {
        int j = jo * 8 + e;
        float u = b[j];
        if (j < Vv && i != j) u = 0.5f * u + 0.5f * X[j];
        u = fmaxf(u, 0.f);
        u16 h, m, l; split3(u, h, m, l);
        vh[e] = (short)h; vm[e] = (short)m; vl[e] = (short)l;
    }
    int ig = i >> 5, r = i & 31, js = jo >> 3, o = jo & 7;
    size_t tb = (size_t)(ig * 16 + js) * 12288 + (size_t)(o * 32 + r) * 16;
    *(s16x8*)(ws + OFF_A0 + tb)        = vh;
    *(s16x8*)(ws + OFF_A0 + tb + 4096) = vm;
    *(s16x8*)(ws + OFF_A0 + tb + 8192) = vl;
}

#define GST(addr, val) \
    asm volatile("global_store_dwordx2 %0, %1, off sc0 sc1" \
                 :: "v"((void*)(addr)), "v"(val) : "memory")
#define MM(acc_, a_, b_) \
    asm("v_mfma_f32_16x16x32_bf16 %0, %1, %2, %0" : "+v"(acc_) : "v"(a_), "v"(b_))

// Persistent: 256 blocks x 512 thr; block = (ig, js). 8 waves: kh = w&1, nq = w>>1.
// Wh/Wm pinned in regs (128 VGPR, volatile asm loads). Wl LDS-resident (128 KB).
// A chunks: reg-staged (coherent GLD) -> LDS dbuf (2x12 KB), counted-vmcnt pipeline,
// one raw s_barrier per chunk (no vmcnt(0) drain in the main loop).
__global__ __launch_bounds__(512, 2)
void mega_kernel(const float* __restrict__ X, const float* __restrict__ b,
                 char* __restrict__ ws) {
    extern __shared__ char smem[];   // Wl 131072 | A slots 2x12288 (red overlays slots)
    const int tid = threadIdx.x, bid = blockIdx.x;
    const int ig = bid >> 4, js = bid & 15;
    const int lane = tid & 63, l15 = lane & 15, l4 = lane >> 4;
    const int w = tid >> 6, kh = w & 1, nq = w >> 1;

    unsigned* flg = (unsigned*)(ws + OFF_FLG);

    // one-time: Wl 64-col slice -> LDS (linear, async)
    {
        const char* src = ws + OFF_WL + (size_t)js * 131072;
#pragma unroll
        for (int q = 0; q < 16; ++q) {
            unsigned u = (unsigned)(q * 512 + tid) * 16u;
            __builtin_amdgcn_global_load_lds(
                (const __attribute__((address_space(1))) void*)(src + u),
                (__attribute__((address_space(3))) void*)(smem + u), 16, 0, 0);
        }
    }
    // one-time: Wh/Wm pinned into registers via volatile loads
    s16x8 Bh[16], Bm[16];
#pragma unroll
    for (int c = 0; c < 16; ++c) {
        size_t ub = (size_t)((((js * 4 + nq) * 16 + c) * 2 + kh) * 64 + l4 * 16 + l15) * 16;
        asm volatile("global_load_dwordx4 %0, %1, off"
                     : "=v"(Bh[c]) : "v"((const void*)(ws + OFF_WH + ub)));
        asm volatile("global_load_dwordx4 %0, %1, off"
                     : "=v"(Bm[c]) : "v"((const void*)(ws + OFF_WM + ub)));
    }
    asm volatile("s_waitcnt vmcnt(0)" ::: "memory");

    const int row = tid >> 4, c4 = (tid & 15) * 4;
    const int i_glob = ig * 32 + row;
    float bb[4];
#pragma unroll
    for (int e = 0; e < 4; ++e) bb[e] = b[js * 64 + c4 + e];
    float* red = (float*)(smem + 131072);

    __syncthreads();   // Wl in LDS, W regs ready

#define GLDA(g, cc) do {                                                              \
        const char* ap_ = tb + (size_t)(cc) * 12288 + (size_t)tid * 8;                \
        asm volatile("global_load_dwordx2 %0, %1, off sc0 sc1"                        \
                     : "=v"((g)[0]) : "v"((const void*)ap_) : "memory");              \
        asm volatile("global_load_dwordx2 %0, %1, off sc0 sc1"                        \
                     : "=v"((g)[1]) : "v"((const void*)(ap_ + 4096)) : "memory");     \
        asm volatile("global_load_dwordx2 %0, %1, off sc0 sc1"                        \
                     : "=v"((g)[2]) : "v"((const void*)(ap_ + 8192)) : "memory");     \
    } while (0)
#define DSWR(slot, g) do {                                                            \
        char* wp_ = smem + 131072 + (size_t)(slot) * 12288 + (size_t)tid * 8;         \
        *(u64*)(wp_) = (g)[0]; *(u64*)(wp_ + 4096) = (g)[1]; *(u64*)(wp_ + 8192) = (g)[2]; \
    } while (0)
#define DSRD(slot, cc) do {                                                           \
        const char* sb_ = smem + 131072 + (size_t)(slot) * 12288;                     \
        _Pragma("unroll")                                                             \
        for (int lv_ = 0; lv_ < 3; ++lv_)                                             \
            _Pragma("unroll")                                                         \
            for (int mf_ = 0; mf_ < 2; ++mf_)                                         \
                Af[lv_][mf_] = *(const s16x8*)(sb_ +                                  \
                    (size_t)(lv_ * 256 + (kh * 4 + l4) * 32 + mf_ * 16 + l15) * 16);  \
        Bl = *(const s16x8*)(smem +                                                   \
                    (size_t)(((cc) * 2 + kh) * 256 + l4 * 64 + nq * 16 + l15) * 16);  \
    } while (0)
#define MFMA12(c) do {                                                                \
        __builtin_amdgcn_s_setprio(1);                                                \
        MM(acc0, Af[0][0], Bh[c]); MM(acc1, Af[0][1], Bh[c]);                         \
        MM(acc0, Af[0][0], Bm[c]); MM(acc1, Af[0][1], Bm[c]);                         \
        MM(acc0, Af[1][0], Bh[c]); MM(acc1, Af[1][1], Bh[c]);                         \
        MM(acc0, Af[0][0], Bl);    MM(acc1, Af[0][1], Bl);                            \
        MM(acc0, Af[2][0], Bh[c]); MM(acc1, Af[2][1], Bh[c]);                         \
        MM(acc0, Af[1][0], Bm[c]); MM(acc1, Af[1][1], Bm[c]);                         \
        __builtin_amdgcn_s_setprio(0);                                                \
    } while (0)

    for (int t = 1; t <= 126; ++t) {
        char* srcA = ws + ((t & 1) ? OFF_A0 : OFF_A1);
        char* dstA = ws + ((t & 1) ? OFF_A1 : OFF_A0);

        // wait all 16 producer tiles of row ig at step t-1 (parallel poll)
        if (tid < 16) {
            while ((int)__hip_atomic_load(&flg[ig * 16 + tid], __ATOMIC_RELAXED,
                                          __HIP_MEMORY_SCOPE_AGENT) < t - 1)
                __builtin_amdgcn_s_sleep(1);
        }
        __syncthreads();
        asm volatile("" ::: "memory");

        const char* tb = srcA + (size_t)ig * 16 * 12288;
        u64 ga[3], gb_[3];
        GLDA(ga, 0);
        GLDA(gb_, 1);
        asm volatile("s_waitcnt vmcnt(3)" ::: "memory");   // chunk0 in regs
        DSWR(0, ga);
        asm volatile("s_waitcnt lgkmcnt(0)" ::: "memory");
        __builtin_amdgcn_s_barrier();
        s16x8 Af[3][2], Bl;
        DSRD(0, 0);

        f32x4 acc0 = (f32x4){0.f, 0.f, 0.f, 0.f};
        f32x4 acc1 = (f32x4){0.f, 0.f, 0.f, 0.f};

#pragma unroll
        for (int c = 0; c < 16; ++c) {
            if (c < 14) {                     // refill the just-freed g buffer with c+2
                if (c & 1) GLDA(gb_, c + 2); else GLDA(ga, c + 2);
            }
            __builtin_amdgcn_sched_barrier(0);
            MFMA12(c);
            __builtin_amdgcn_sched_barrier(0);
            if (c < 15) {
                if (c < 14) asm volatile("s_waitcnt vmcnt(3)" ::: "memory");  // c+1 done
                else        asm volatile("s_waitcnt vmcnt(0)" ::: "memory");
                if (c & 1) DSWR((c + 1) & 1, ga); else DSWR((c + 1) & 1, gb_);
                asm volatile("s_waitcnt lgkmcnt(0)" ::: "memory");
                __builtin_amdgcn_s_barrier();
                DSRD((c + 1) & 1, c + 1);
            }
        }

        __builtin_amdgcn_s_barrier();         // all waves done with A slots (red overlay)
        asm volatile("s_nop 7\n\ts_nop 7");   // MFMA->VALU read hazard guard

        // kh-pair reduction through LDS
#pragma unroll
        for (int mf = 0; mf < 2; ++mf)
#pragma unroll
            for (int r = 0; r < 4; ++r)
                red[w * 512 + (mf * 16 + l4 * 4 + r) * 16 + l15] =
                    (mf == 0) ? acc0[r] : acc1[r];
        __syncthreads();

        // epilogue: 4 outputs/thread, bias + mask + relu + exact re-split, coherent store
        {
            const int nqo = c4 >> 4, cl0 = c4 & 15;
            float4 p0 = *(const float4*)&red[(nqo * 2 + 0) * 512 + row * 16 + cl0];
            float4 p1 = *(const float4*)&red[(nqo * 2 + 1) * 512 + row * 16 + cl0];
            float s[4] = {p0.x + p1.x, p0.y + p1.y, p0.z + p1.z, p0.w + p1.w};
            const float* xt = X + (size_t)t * Vv;
            u64 ph = 0, pm = 0, pl = 0;
#pragma unroll
            for (int e = 0; e < 4; ++e) {
                int j = js * 64 + c4 + e;
                float u = s[e] + bb[e];
                if (js < 8 && i_glob != j) u = 0.5f * u + 0.5f * xt[j];
                u = fmaxf(u, 0.f);
                u16 h, m, l; split3(u, h, m, l);
                ph |= (u64)h << (e * 16);
                pm |= (u64)m << (e * 16);
                pl |= (u64)l << (e * 16);
            }
            size_t tbo = (size_t)(ig * 16 + js) * 12288
                       + (size_t)((c4 >> 3) * 32 + row) * 16 + (c4 & 7) * 2;
            GST(dstA + tbo, ph);
            GST(dstA + tbo + 4096, pm);
            GST(dstA + tbo + 8192, pl);
        }
        asm volatile("s_waitcnt vmcnt(0)" ::: "memory");
        __syncthreads();   // all waves' coherent stores drained
        if (tid == 0)
            __hip_atomic_store(&flg[ig * 16 + js], (unsigned)t, __ATOMIC_RELAXED,
                               __HIP_MEMORY_SCOPE_AGENT);
    }
#undef GLDA
#undef DSWR
#undef DSRD
#undef MFMA12
}

// Final: out[i] = dot(R126[i,:], W[i,:]) + b[i]; R126 in A0 tiles (h+m+l exact)
__global__ void diag_kernel(const char* __restrict__ ws, const float* __restrict__ W,
                            const float* __restrict__ b, float* __restrict__ out) {
    int i = blockIdx.x, lane = threadIdx.x;
    const char* A0 = ws + OFF_A0;
    float s = 0.f;
#pragma unroll
    for (int rep = 0; rep < 2; ++rep) {
        int ko = lane + rep * 64;                 // k-octet 0..127
        int js = ko >> 3, o = ko & 7;
        size_t tb = (size_t)((i >> 5) * 16 + js) * 12288
                  + (size_t)(o * 32 + (i & 31)) * 16;
        s16x8 vh = *(const s16x8*)(A0 + tb);
        s16x8 vm = *(const s16x8*)(A0 + tb + 4096);
        s16x8 vl = *(const s16x8*)(A0 + tb + 8192);
        const float* wr = W + (size_t)i * Ff + ko * 8;
#pragma unroll
        for (int e = 0; e < 8; ++e)
            s += (bf2f(vh[e]) + bf2f(vm[e]) + bf2f(vl[e])) * wr[e];
    }
#pragma unroll
    for (int off = 32; off > 0; off >>= 1) s += __shfl_down(s, off);
    if (lane == 0) out[i] = s + b[i];
}

extern "C" void kernel_launch(void* const* d_in, const int* in_sizes, int n_in,
                              void* d_out, int out_size, void* d_ws, size_t ws_size,
                              hipStream_t stream) {
    const float* X = (const float*)d_in[0];   // (128, 512)
    const float* W = (const float*)d_in[1];   // (1024, 1024)
    const float* b = (const float*)d_in[2];   // (1024,)
    float* out = (float*)d_out;
    char* ws = (char*)d_ws;

    hipFuncSetAttribute(reinterpret_cast<const void*>(mega_kernel),
                        hipFuncAttributeMaxDynamicSharedMemorySize, 155648);

    wsplit_kernel<<<512, 256, 0, stream>>>(W, ws);
    init_kernel<<<256, 256, 0, stream>>>(X, b, ws);
    mega_kernel<<<256, 512, 155648, stream>>>(X, b, ws);
    diag_kernel<<<512, 64, 0, stream>>>(ws, W, b, out);
}

// Round 9
// 1143.178 us; speedup vs baseline: 1.9821x; 1.0029x over previous
//
#include <hip/hip_runtime.h>
#include <stdint.h>

#define Vv 512
#define Ff 1024

typedef unsigned short u16;
typedef unsigned long long u64;
typedef __attribute__((ext_vector_type(8))) short s16x8;
typedef __attribute__((ext_vector_type(4))) float f32x4;

// workspace layout (bytes)
#define OFF_WH  (0ull)
#define OFF_WM  (2ull << 20)
#define OFF_WL  (4ull << 20)
#define OFF_A0  (6ull << 20)
#define OFF_A1  (9ull << 20)
#define OFF_FLG (12ull << 20)

// A buffer: 256 tiles (ig 16 x js 16), tile = 12288 B: [lv 3][o 8][r 32] 16B units;
// element (i=ig*32+r, j=js*64+o*8+e) at tile*12288 + lv*4096 + (o*32+r)*16 + e*2.

// Exact 3-way bf16 truncation split: v == h + m + l (bit-exact, 24 mantissa bits)
__device__ __forceinline__ void split3(float v, u16& h, u16& m, u16& l) {
    unsigned u = __float_as_uint(v);
    float fh = __uint_as_float(u & 0xFFFF0000u);
    h = (u16)(u >> 16);
    float r1 = v - fh;                         // exact
    unsigned u1 = __float_as_uint(r1);
    float fm = __uint_as_float(u1 & 0xFFFF0000u);
    m = (u16)(u1 >> 16);
    float r2 = r1 - fm;                        // exact
    l = (u16)(__float_as_uint(r2) >> 16);
}

__device__ __forceinline__ float bf2f(short v) {
    return __uint_as_float(((unsigned)(u16)v) << 16);
}

// W planes. Wh/Wm frag-major: unit = (((js*4+nq)*16+c)*2+kh)*64 + o*16 + col.
// Wl (per js-block 8192 units, LDS-linear): unit = js*8192 + (c*2+kh)*256 + o*64 + nq*16 + col.
__global__ void wsplit_kernel(const float* __restrict__ W, char* __restrict__ ws) {
    int idx = blockIdx.x * 256 + threadIdx.x;   // 0..131071 (j x k-octet)
    int j = idx >> 7, ko = idx & 127;
    const float* wr = W + (size_t)j * Ff + ko * 8;
    s16x8 vh, vm, vl;
#pragma unroll
    for (int e = 0; e < 8; ++e) {
        u16 h, m, l; split3(wr[e], h, m, l);
        vh[e] = (short)h; vm[e] = (short)m; vl[e] = (short)l;
    }
    int js = j >> 6, nq = (j >> 4) & 3, col = j & 15;
    int c = ko >> 3, kh = (ko >> 2) & 1, o = ko & 3;
    unsigned uhm = (unsigned)((((js * 4 + nq) * 16 + c) * 2 + kh) * 64 + o * 16 + col);
    unsigned ul  = (unsigned)(js * 8192 + (c * 2 + kh) * 256 + o * 64 + nq * 16 + col);
    *(s16x8*)(ws + OFF_WH + (size_t)uhm * 16) = vh;
    *(s16x8*)(ws + OFF_WM + (size_t)uhm * 16) = vm;
    *(s16x8*)(ws + OFF_WL + (size_t)ul * 16)  = vl;
}

// t=0 state into A0 tiles + zero the 256 tile flags
__global__ void init_kernel(const float* __restrict__ X, const float* __restrict__ b,
                            char* __restrict__ ws) {
    int idx = blockIdx.x * 256 + threadIdx.x;   // 0..65535 (i x j-octet)
    if (idx < 256) ((unsigned*)(ws + OFF_FLG))[idx] = 0u;
    int i = idx >> 7, jo = idx & 127;
    s16x8 vh, vm, vl;
#pragma unroll
    for (int e = 0; e < 8; ++e) {
        int j = jo * 8 + e;
        float u = b[j];
        if (j < Vv && i != j) u = 0.5f * u + 0.5f * X[j];
        u = fmaxf(u, 0.f);
        u16 h, m, l; split3(u, h, m, l);
        vh[e] = (short)h; vm[e] = (short)m; vl[e] = (short)l;
    }
    int ig = i >> 5, r = i & 31, js = jo >> 3, o = jo & 7;
    size_t tb = (size_t)(ig * 16 + js) * 12288 + (size_t)(o * 32 + r) * 16;
    *(s16x8*)(ws + OFF_A0 + tb)        = vh;
    *(s16x8*)(ws + OFF_A0 + tb + 4096) = vm;
    *(s16x8*)(ws + OFF_A0 + tb + 8192) = vl;
}

#define GST(addr, val) \
    asm volatile("global_store_dwordx2 %0, %1, off sc0 sc1" \
                 :: "v"((void*)(addr)), "v"(val) : "memory")
#define MM(acc_, a_, b_) \
    asm("v_mfma_f32_16x16x32_bf16 %0, %1, %2, %0" : "+v"(acc_) : "v"(a_), "v"(b_))

// Persistent: 256 blocks x 512 thr; block = (ig, js). 8 waves: kh = w&1, nq = w>>1.
// Wh/Wm pinned in regs (128 VGPR). __launch_bounds__(512,1): no register cap ->
// allocator keeps W resident (~200 VGPR, still 2 waves/SIMD = full residency).
// Wl LDS-resident (128 KB). A chunks: reg-staged coherent GLD -> LDS dbuf (2x12 KB),
// counted-vmcnt pipeline, one raw s_barrier per chunk.
__global__ __launch_bounds__(512, 1)
void mega_kernel(const float* __restrict__ X, const float* __restrict__ b,
                 char* __restrict__ ws) {
    extern __shared__ char smem[];   // Wl 131072 | A slots 2x12288 (red overlays slots)
    const int tid = threadIdx.x, bid = blockIdx.x;
    const int ig = bid >> 4, js = bid & 15;
    const int lane = tid & 63, l15 = lane & 15, l4 = lane >> 4;
    const int w = tid >> 6, kh = w & 1, nq = w >> 1;

    unsigned* flg = (unsigned*)(ws + OFF_FLG);

    // one-time: Wl 64-col slice -> LDS (linear, async)
    {
        const char* src = ws + OFF_WL + (size_t)js * 131072;
#pragma unroll
        for (int q = 0; q < 16; ++q) {
            unsigned u = (unsigned)(q * 512 + tid) * 16u;
            __builtin_amdgcn_global_load_lds(
                (const __attribute__((address_space(1))) void*)(src + u),
                (__attribute__((address_space(3))) void*)(smem + u), 16, 0, 0);
        }
    }
    // one-time: Wh/Wm pinned into registers via volatile loads
    s16x8 Bh[16], Bm[16];
#pragma unroll
    for (int c = 0; c < 16; ++c) {
        size_t ub = (size_t)((((js * 4 + nq) * 16 + c) * 2 + kh) * 64 + l4 * 16 + l15) * 16;
        asm volatile("global_load_dwordx4 %0, %1, off"
                     : "=v"(Bh[c]) : "v"((const void*)(ws + OFF_WH + ub)));
        asm volatile("global_load_dwordx4 %0, %1, off"
                     : "=v"(Bm[c]) : "v"((const void*)(ws + OFF_WM + ub)));
    }
    asm volatile("s_waitcnt vmcnt(0)" ::: "memory");

    const int row = tid >> 4, c4 = (tid & 15) * 4;
    const int i_glob = ig * 32 + row;
    float bb[4];
#pragma unroll
    for (int e = 0; e < 4; ++e) bb[e] = b[js * 64 + c4 + e];
    float* red = (float*)(smem + 131072);

    __syncthreads();   // Wl in LDS, W regs ready

#define GLDA(g, cc) do {                                                              \
        const char* ap_ = tb + (size_t)(cc) * 12288 + (size_t)tid * 8;                \
        asm volatile("global_load_dwordx2 %0, %1, off sc0 sc1"                        \
                     : "=v"((g)[0]) : "v"((const void*)ap_) : "memory");              \
        asm volatile("global_load_dwordx2 %0, %1, off sc0 sc1"                        \
                     : "=v"((g)[1]) : "v"((const void*)(ap_ + 4096)) : "memory");     \
        asm volatile("global_load_dwordx2 %0, %1, off sc0 sc1"                        \
                     : "=v"((g)[2]) : "v"((const void*)(ap_ + 8192)) : "memory");     \
    } while (0)
#define DSWR(slot, g) do {                                                            \
        char* wp_ = smem + 131072 + (size_t)(slot) * 12288 + (size_t)tid * 8;         \
        *(u64*)(wp_) = (g)[0]; *(u64*)(wp_ + 4096) = (g)[1]; *(u64*)(wp_ + 8192) = (g)[2]; \
    } while (0)
#define DSRD(slot, cc) do {                                                           \
        const char* sb_ = smem + 131072 + (size_t)(slot) * 12288;                     \
        _Pragma("unroll")                                                             \
        for (int lv_ = 0; lv_ < 3; ++lv_)                                             \
            _Pragma("unroll")                                                         \
            for (int mf_ = 0; mf_ < 2; ++mf_)                                         \
                Af[lv_][mf_] = *(const s16x8*)(sb_ +                                  \
                    (size_t)(lv_ * 256 + (kh * 4 + l4) * 32 + mf_ * 16 + l15) * 16);  \
        Bl = *(const s16x8*)(smem +                                                   \
                    (size_t)(((cc) * 2 + kh) * 256 + l4 * 64 + nq * 16 + l15) * 16);  \
    } while (0)
#define MFMA12(c) do {                                                                \
        __builtin_amdgcn_s_setprio(1);                                                \
        MM(acc0, Af[0][0], Bh[c]); MM(acc1, Af[0][1], Bh[c]);                         \
        MM(acc0, Af[0][0], Bm[c]); MM(acc1, Af[0][1], Bm[c]);                         \
        MM(acc0, Af[1][0], Bh[c]); MM(acc1, Af[1][1], Bh[c]);                         \
        MM(acc0, Af[0][0], Bl);    MM(acc1, Af[0][1], Bl);                            \
        MM(acc0, Af[2][0], Bh[c]); MM(acc1, Af[2][1], Bh[c]);                         \
        MM(acc0, Af[1][0], Bm[c]); MM(acc1, Af[1][1], Bm[c]);                         \
        __builtin_amdgcn_s_setprio(0);                                                \
    } while (0)

    for (int t = 1; t <= 126; ++t) {
        char* srcA = ws + ((t & 1) ? OFF_A0 : OFF_A1);
        char* dstA = ws + ((t & 1) ? OFF_A1 : OFF_A0);

        // wait all 16 producer tiles of row ig at step t-1 (parallel poll)
        if (tid < 16) {
            while ((int)__hip_atomic_load(&flg[ig * 16 + tid], __ATOMIC_RELAXED,
                                          __HIP_MEMORY_SCOPE_AGENT) < t - 1)
                __builtin_amdgcn_s_sleep(1);
        }
        __syncthreads();
        asm volatile("" ::: "memory");

        const char* tb = srcA + (size_t)ig * 16 * 12288;
        u64 ga[3], gb_[3];
        GLDA(ga, 0);
        GLDA(gb_, 1);
        asm volatile("s_waitcnt vmcnt(3)" ::: "memory");   // chunk0 in regs
        DSWR(0, ga);
        asm volatile("s_waitcnt lgkmcnt(0)" ::: "memory");
        __builtin_amdgcn_s_barrier();
        s16x8 Af[3][2], Bl;
        DSRD(0, 0);

        f32x4 acc0 = (f32x4){0.f, 0.f, 0.f, 0.f};
        f32x4 acc1 = (f32x4){0.f, 0.f, 0.f, 0.f};

#pragma unroll
        for (int c = 0; c < 16; ++c) {
            if (c < 14) {                     // refill the just-freed g buffer with c+2
                if (c & 1) GLDA(gb_, c + 2); else GLDA(ga, c + 2);
            }
            __builtin_amdgcn_sched_barrier(0);
            MFMA12(c);
            __builtin_amdgcn_sched_barrier(0);
            if (c < 15) {
                if (c < 14) asm volatile("s_waitcnt vmcnt(3)" ::: "memory");  // c+1 done
                else        asm volatile("s_waitcnt vmcnt(0)" ::: "memory");
                if (c & 1) DSWR((c + 1) & 1, ga); else DSWR((c + 1) & 1, gb_);
                asm volatile("s_waitcnt lgkmcnt(0)" ::: "memory");
                __builtin_amdgcn_s_barrier();
                DSRD((c + 1) & 1, c + 1);
            }
        }

        __builtin_amdgcn_s_barrier();         // all waves done with A slots (red overlay)
        asm volatile("s_nop 7\n\ts_nop 7");   // MFMA->VALU read hazard guard

        // kh-pair reduction through LDS
#pragma unroll
        for (int mf = 0; mf < 2; ++mf)
#pragma unroll
            for (int r = 0; r < 4; ++r)
                red[w * 512 + (mf * 16 + l4 * 4 + r) * 16 + l15] =
                    (mf == 0) ? acc0[r] : acc1[r];
        __syncthreads();

        // epilogue: 4 outputs/thread, bias + mask + relu + exact re-split, coherent store
        {
            const int nqo = c4 >> 4, cl0 = c4 & 15;
            float4 p0 = *(const float4*)&red[(nqo * 2 + 0) * 512 + row * 16 + cl0];
            float4 p1 = *(const float4*)&red[(nqo * 2 + 1) * 512 + row * 16 + cl0];
            float s[4] = {p0.x + p1.x, p0.y + p1.y, p0.z + p1.z, p0.w + p1.w};
            const float* xt = X + (size_t)t * Vv;
            u64 ph = 0, pm = 0, pl = 0;
#pragma unroll
            for (int e = 0; e < 4; ++e) {
                int j = js * 64 + c4 + e;
                float u = s[e] + bb[e];
                if (js < 8 && i_glob != j) u = 0.5f * u + 0.5f * xt[j];
                u = fmaxf(u, 0.f);
                u16 h, m, l; split3(u, h, m, l);
                ph |= (u64)h << (e * 16);
                pm |= (u64)m << (e * 16);
                pl |= (u64)l << (e * 16);
            }
            size_t tbo = (size_t)(ig * 16 + js) * 12288
                       + (size_t)((c4 >> 3) * 32 + row) * 16 + (c4 & 7) * 2;
            GST(dstA + tbo, ph);
            GST(dstA + tbo + 4096, pm);
            GST(dstA + tbo + 8192, pl);
        }
        asm volatile("s_waitcnt vmcnt(0)" ::: "memory");
        __syncthreads();   // all waves' coherent stores drained
        if (tid == 0)
            __hip_atomic_store(&flg[ig * 16 + js], (unsigned)t, __ATOMIC_RELAXED,
                               __HIP_MEMORY_SCOPE_AGENT);
    }
#undef GLDA
#undef DSWR
#undef DSRD
#undef MFMA12
}

// Final: out[i] = dot(R126[i,:], W[i,:]) + b[i]; R126 in A0 tiles (h+m+l exact)
__global__ void diag_kernel(const char* __restrict__ ws, const float* __restrict__ W,
                            const float* __restrict__ b, float* __restrict__ out) {
    int i = blockIdx.x, lane = threadIdx.x;
    const char* A0 = ws + OFF_A0;
    float s = 0.f;
#pragma unroll
    for (int rep = 0; rep < 2; ++rep) {
        int ko = lane + rep * 64;                 // k-octet 0..127
        int js = ko >> 3, o = ko & 7;
        size_t tb = (size_t)((i >> 5) * 16 + js) * 12288
                  + (size_t)(o * 32 + (i & 31)) * 16;
        s16x8 vh = *(const s16x8*)(A0 + tb);
        s16x8 vm = *(const s16x8*)(A0 + tb + 4096);
        s16x8 vl = *(const s16x8*)(A0 + tb + 8192);
        const float* wr = W + (size_t)i * Ff + ko * 8;
#pragma unroll
        for (int e = 0; e < 8; ++e)
            s += (bf2f(vh[e]) + bf2f(vm[e]) + bf2f(vl[e])) * wr[e];
    }
#pragma unroll
    for (int off = 32; off > 0; off >>= 1) s += __shfl_down(s, off);
    if (lane == 0) out[i] = s + b[i];
}

extern "C" void kernel_launch(void* const* d_in, const int* in_sizes, int n_in,
                              void* d_out, int out_size, void* d_ws, size_t ws_size,
                              hipStream_t stream) {
    const float* X = (const float*)d_in[0];   // (128, 512)
    const float* W = (const float*)d_in[1];   // (1024, 1024)
    const float* b = (const float*)d_in[2];   // (1024,)
    float* out = (float*)d_out;
    char* ws = (char*)d_ws;

    hipFuncSetAttribute(reinterpret_cast<const void*>(mega_kernel),
                        hipFuncAttributeMaxDynamicSharedMemorySize, 155648);

    wsplit_kernel<<<512, 256, 0, stream>>>(W, ws);
    init_kernel<<<256, 256, 0, stream>>>(X, b, ws);
    mega_kernel<<<256, 512, 155648, stream>>>(X, b, ws);
    diag_kernel<<<512, 64, 0, stream>>>(ws, W, b, out);
}

// Round 10
// 1093.117 us; speedup vs baseline: 2.0729x; 1.0458x over previous
//
#include <hip/hip_runtime.h>
#include <stdint.h>

#define Vv 512
#define Ff 1024

typedef unsigned short u16;
typedef unsigned long long u64;
typedef __attribute__((ext_vector_type(8))) short s16x8;
typedef __attribute__((ext_vector_type(4))) float f32x4;

// workspace layout (bytes)
#define OFF_WH  (0ull)
#define OFF_WM  (2ull << 20)
#define OFF_WL  (4ull << 20)
#define OFF_A0  (6ull << 20)
#define OFF_A1  (9ull << 20)
#define OFF_FLG (12ull << 20)

// A buffer: 256 tiles (ig 16 x js 16), tile = 12288 B: [lv 3][o 8][r 32] 16B units;
// element (i=ig*32+r, j=js*64+o*8+e) at tile*12288 + lv*4096 + (o*32+r)*16 + e*2.

// Exact 3-way bf16 truncation split: v == h + m + l (bit-exact, 24 mantissa bits)
__device__ __forceinline__ void split3(float v, u16& h, u16& m, u16& l) {
    unsigned u = __float_as_uint(v);
    float fh = __uint_as_float(u & 0xFFFF0000u);
    h = (u16)(u >> 16);
    float r1 = v - fh;                         // exact
    unsigned u1 = __float_as_uint(r1);
    float fm = __uint_as_float(u1 & 0xFFFF0000u);
    m = (u16)(u1 >> 16);
    float r2 = r1 - fm;                        // exact
    l = (u16)(__float_as_uint(r2) >> 16);
}

__device__ __forceinline__ float bf2f(short v) {
    return __uint_as_float(((unsigned)(u16)v) << 16);
}

// W planes. Wh/Wm frag-major: unit = (((js*4+nq)*16+c)*2+kh)*64 + o*16 + col.
// Wl (per js-block 8192 units, LDS-linear): unit = js*8192 + (c*2+kh)*256 + o*64 + nq*16 + col.
__global__ void wsplit_kernel(const float* __restrict__ W, char* __restrict__ ws) {
    int idx = blockIdx.x * 256 + threadIdx.x;   // 0..131071 (j x k-octet)
    int j = idx >> 7, ko = idx & 127;
    const float* wr = W + (size_t)j * Ff + ko * 8;
    s16x8 vh, vm, vl;
#pragma unroll
    for (int e = 0; e < 8; ++e) {
        u16 h, m, l; split3(wr[e], h, m, l);
        vh[e] = (short)h; vm[e] = (short)m; vl[e] = (short)l;
    }
    int js = j >> 6, nq = (j >> 4) & 3, col = j & 15;
    int c = ko >> 3, kh = (ko >> 2) & 1, o = ko & 3;
    unsigned uhm = (unsigned)((((js * 4 + nq) * 16 + c) * 2 + kh) * 64 + o * 16 + col);
    unsigned ul  = (unsigned)(js * 8192 + (c * 2 + kh) * 256 + o * 64 + nq * 16 + col);
    *(s16x8*)(ws + OFF_WH + (size_t)uhm * 16) = vh;
    *(s16x8*)(ws + OFF_WM + (size_t)uhm * 16) = vm;
    *(s16x8*)(ws + OFF_WL + (size_t)ul * 16)  = vl;
}

// t=0 state into A0 tiles + zero the 256 tile flags
__global__ void init_kernel(const float* __restrict__ X, const float* __restrict__ b,
                            char* __restrict__ ws) {
    int idx = blockIdx.x * 256 + threadIdx.x;   // 0..65535 (i x j-octet)
    if (idx < 256) ((unsigned*)(ws + OFF_FLG))[idx] = 0u;
    int i = idx >> 7, jo = idx & 127;
    s16x8 vh, vm, vl;
#pragma unroll
    for (int e = 0; e < 8; ++e) {
        int j = jo * 8 + e;
        float u = b[j];
        if (j < Vv && i != j) u = 0.5f * u + 0.5f * X[j];
        u = fmaxf(u, 0.f);
        u16 h, m, l; split3(u, h, m, l);
        vh[e] = (short)h; vm[e] = (short)m; vl[e] = (short)l;
    }
    int ig = i >> 5, r = i & 31, js = jo >> 3, o = jo & 7;
    size_t tb = (size_t)(ig * 16 + js) * 12288 + (size_t)(o * 32 + r) * 16;
    *(s16x8*)(ws + OFF_A0 + tb)        = vh;
    *(s16x8*)(ws + OFF_A0 + tb + 4096) = vm;
    *(s16x8*)(ws + OFF_A0 + tb + 8192) = vl;
}

#define GST(addr, val) \
    asm volatile("global_store_dwordx2 %0, %1, off sc0 sc1" \
                 :: "v"((void*)(addr)), "v"(val) : "memory")
#define MM(acc_, a_, b_) \
    asm("v_mfma_f32_16x16x32_bf16 %0, %1, %2, %0" : "+v"(acc_) : "v"(a_), "v"(b_))

// Persistent: 256 blocks x 512 thr; block = (ig, js). 8 waves: kh = w&1, nq = w>>1.
// Wh/Wm register-resident as 32 INDIVIDUALLY NAMED s16x8 scalars (no arrays ->
// no alloca -> no scratch; rule #20). Wl LDS-resident (128 KB). A chunks:
// reg-staged coherent GLD -> LDS dbuf (2x12 KB), counted-vmcnt pipeline,
// one raw s_barrier per chunk; all 16 chunks macro-expanded with literal consts.
__global__ __launch_bounds__(512, 2)
void mega_kernel(const float* __restrict__ X, const float* __restrict__ b,
                 char* __restrict__ ws) {
    extern __shared__ char smem[];   // Wl 131072 | A slots 2x12288 (red overlays slots)
    const int tid = threadIdx.x, bid = blockIdx.x;
    const int ig = bid >> 4, js = bid & 15;
    const int lane = tid & 63, l15 = lane & 15, l4 = lane >> 4;
    const int w = tid >> 6, kh = w & 1, nq = w >> 1;

    unsigned* flg = (unsigned*)(ws + OFF_FLG);

    // one-time: Wl 64-col slice -> LDS (linear, async)
    {
        const char* src = ws + OFF_WL + (size_t)js * 131072;
#pragma unroll
        for (int q = 0; q < 16; ++q) {
            unsigned u = (unsigned)(q * 512 + tid) * 16u;
            __builtin_amdgcn_global_load_lds(
                (const __attribute__((address_space(1))) void*)(src + u),
                (__attribute__((address_space(3))) void*)(smem + u), 16, 0, 0);
        }
    }

    // one-time: Wh/Wm -> 32 named register scalars (volatile loads, executed once)
    s16x8 Bh0, Bh1, Bh2, Bh3, Bh4, Bh5, Bh6, Bh7, Bh8, Bh9, Bh10, Bh11, Bh12, Bh13, Bh14, Bh15;
    s16x8 Bm0, Bm1, Bm2, Bm3, Bm4, Bm5, Bm6, Bm7, Bm8, Bm9, Bm10, Bm11, Bm12, Bm13, Bm14, Bm15;
    {
        const char* wbase = ws + OFF_WH +
            (size_t)(((((js * 4 + nq) * 16) * 2 + kh) * 64) + l4 * 16 + l15) * 16;
#define LOADW(c) do {                                                                  \
        asm volatile("global_load_dwordx4 %0, %1, off"                                 \
                     : "=v"(Bh##c) : "v"((const void*)(wbase + (c) * 2048)));          \
        asm volatile("global_load_dwordx4 %0, %1, off"                                 \
                     : "=v"(Bm##c) : "v"((const void*)(wbase + (c) * 2048 + (2ull << 20)))); \
    } while (0)
        LOADW(0);  LOADW(1);  LOADW(2);  LOADW(3);
        LOADW(4);  LOADW(5);  LOADW(6);  LOADW(7);
        LOADW(8);  LOADW(9);  LOADW(10); LOADW(11);
        LOADW(12); LOADW(13); LOADW(14); LOADW(15);
#undef LOADW
    }
    asm volatile("s_waitcnt vmcnt(0)" ::: "memory");

    const int row = tid >> 4, c4 = (tid & 15) * 4;
    const int i_glob = ig * 32 + row;
    const float4 bbv = *(const float4*)(b + js * 64 + c4);
    float* red = (float*)(smem + 131072);

    // per-thread constant LDS offsets
    const unsigned abase = (unsigned)(((kh * 4 + l4) * 32 + l15) * 16);
    const unsigned a00 = abase,          a01 = abase + 256;             // lv0, mf0/1
    const unsigned a10 = abase + 4096,   a11 = abase + 4096 + 256;      // lv1
    const unsigned a20 = abase + 8192,   a21 = abase + 8192 + 256;      // lv2
    const unsigned bloff = (unsigned)(kh * 4096 + (l4 * 64 + nq * 16 + l15) * 16);

    __syncthreads();   // Wl in LDS (barrier drains vmcnt), W regs ready

    s16x8 Af00, Af01, Af10, Af11, Af20, Af21, Bl;
    u64 ga0, ga1, ga2, gb0, gb1, gb2;

#define GLDA3(g0_, g1_, g2_, cc) do {                                                  \
        const char* ap_ = tb + (size_t)((cc) * 12288) + (size_t)tid * 8;               \
        asm volatile("global_load_dwordx2 %0, %1, off sc0 sc1"                         \
                     : "=v"(g0_) : "v"((const void*)ap_) : "memory");                  \
        asm volatile("global_load_dwordx2 %0, %1, off sc0 sc1"                         \
                     : "=v"(g1_) : "v"((const void*)(ap_ + 4096)) : "memory");         \
        asm volatile("global_load_dwordx2 %0, %1, off sc0 sc1"                         \
                     : "=v"(g2_) : "v"((const void*)(ap_ + 8192)) : "memory");         \
    } while (0)
#define DSWR3(slot, g0_, g1_, g2_) do {                                                \
        char* wp_ = smem + 131072 + (slot) * 12288 + (size_t)tid * 8;                  \
        *(u64*)(wp_) = g0_; *(u64*)(wp_ + 4096) = g1_; *(u64*)(wp_ + 8192) = g2_;      \
    } while (0)
#define DSRD7(slot, cc) do {                                                           \
        const char* sb_ = smem + 131072 + (slot) * 12288;                              \
        Af00 = *(const s16x8*)(sb_ + a00); Af01 = *(const s16x8*)(sb_ + a01);          \
        Af10 = *(const s16x8*)(sb_ + a10); Af11 = *(const s16x8*)(sb_ + a11);          \
        Af20 = *(const s16x8*)(sb_ + a20); Af21 = *(const s16x8*)(sb_ + a21);          \
        Bl = *(const s16x8*)(smem + (cc) * 8192 + bloff);                              \
    } while (0)
#define MFMA12(c) do {                                                                 \
        __builtin_amdgcn_s_setprio(1);                                                 \
        MM(acc0, Af00, Bh##c); MM(acc1, Af01, Bh##c);                                  \
        MM(acc0, Af00, Bm##c); MM(acc1, Af01, Bm##c);                                  \
        MM(acc0, Af10, Bh##c); MM(acc1, Af11, Bh##c);                                  \
        MM(acc0, Af00, Bl);    MM(acc1, Af01, Bl);                                     \
        MM(acc0, Af20, Bh##c); MM(acc1, Af21, Bh##c);                                  \
        MM(acc0, Af10, Bm##c); MM(acc1, Af11, Bm##c);                                  \
        __builtin_amdgcn_s_setprio(0);                                                 \
    } while (0)
// middle chunk: prefetch P with chunk c+2, compute c, hand off c+1
#define CHUNK_MID(c, P0, P1, P2, Q0, Q1, Q2) do {                                      \
        GLDA3(P0, P1, P2, (c) + 2);                                                    \
        __builtin_amdgcn_sched_barrier(0);                                             \
        MFMA12(c);                                                                     \
        __builtin_amdgcn_sched_barrier(0);                                             \
        asm volatile("s_waitcnt vmcnt(3)" ::: "memory");                               \
        DSWR3(((c) + 1) & 1, Q0, Q1, Q2);                                              \
        asm volatile("s_waitcnt lgkmcnt(0)" ::: "memory");                             \
        __builtin_amdgcn_s_barrier();                                                  \
        DSRD7(((c) + 1) & 1, (c) + 1);                                                 \
    } while (0)

    for (int t = 1; t <= 126; ++t) {
        char* srcA = ws + ((t & 1) ? OFF_A0 : OFF_A1);
        char* dstA = ws + ((t & 1) ? OFF_A1 : OFF_A0);

        // wait all 16 producer tiles of row ig at step t-1 (parallel poll)
        if (tid < 16) {
            while ((int)__hip_atomic_load(&flg[ig * 16 + tid], __ATOMIC_RELAXED,
                                          __HIP_MEMORY_SCOPE_AGENT) < t - 1)
                __builtin_amdgcn_s_sleep(1);
        }
        __syncthreads();
        asm volatile("" ::: "memory");

        const char* tb = srcA + (size_t)ig * 16 * 12288;
        GLDA3(ga0, ga1, ga2, 0);
        GLDA3(gb0, gb1, gb2, 1);
        asm volatile("s_waitcnt vmcnt(3)" ::: "memory");   // chunk0 in regs
        DSWR3(0, ga0, ga1, ga2);
        asm volatile("s_waitcnt lgkmcnt(0)" ::: "memory");
        __builtin_amdgcn_s_barrier();
        DSRD7(0, 0);

        f32x4 acc0 = (f32x4){0.f, 0.f, 0.f, 0.f};
        f32x4 acc1 = (f32x4){0.f, 0.f, 0.f, 0.f};

        CHUNK_MID(0,  ga0, ga1, ga2, gb0, gb1, gb2);
        CHUNK_MID(1,  gb0, gb1, gb2, ga0, ga1, ga2);
        CHUNK_MID(2,  ga0, ga1, ga2, gb0, gb1, gb2);
        CHUNK_MID(3,  gb0, gb1, gb2, ga0, ga1, ga2);
        CHUNK_MID(4,  ga0, ga1, ga2, gb0, gb1, gb2);
        CHUNK_MID(5,  gb0, gb1, gb2, ga0, ga1, ga2);
        CHUNK_MID(6,  ga0, ga1, ga2, gb0, gb1, gb2);
        CHUNK_MID(7,  gb0, gb1, gb2, ga0, ga1, ga2);
        CHUNK_MID(8,  ga0, ga1, ga2, gb0, gb1, gb2);
        CHUNK_MID(9,  gb0, gb1, gb2, ga0, ga1, ga2);
        CHUNK_MID(10, ga0, ga1, ga2, gb0, gb1, gb2);
        CHUNK_MID(11, gb0, gb1, gb2, ga0, ga1, ga2);
        CHUNK_MID(12, ga0, ga1, ga2, gb0, gb1, gb2);
        CHUNK_MID(13, gb0, gb1, gb2, ga0, ga1, ga2);
        // c = 14: no prefetch; drain and hand off chunk 15
        MFMA12(14);
        asm volatile("s_waitcnt vmcnt(0)" ::: "memory");
        DSWR3(1, gb0, gb1, gb2);
        asm volatile("s_waitcnt lgkmcnt(0)" ::: "memory");
        __builtin_amdgcn_s_barrier();
        DSRD7(1, 15);
        // c = 15
        MFMA12(15);

        __builtin_amdgcn_s_barrier();         // all waves done with A slots (red overlay)
        asm volatile("s_nop 7\n\ts_nop 7");   // MFMA->VALU read hazard guard

        // kh-pair reduction through LDS
#pragma unroll
        for (int r = 0; r < 4; ++r)
            red[w * 512 + (l4 * 4 + r) * 16 + l15] = acc0[r];
#pragma unroll
        for (int r = 0; r < 4; ++r)
            red[w * 512 + (16 + l4 * 4 + r) * 16 + l15] = acc1[r];
        __syncthreads();

        // epilogue: 4 outputs/thread, bias + mask + relu + exact re-split, coherent store
        {
            const int nqo = c4 >> 4, cl0 = c4 & 15;
            float4 p0 = *(const float4*)&red[(nqo * 2 + 0) * 512 + row * 16 + cl0];
            float4 p1 = *(const float4*)&red[(nqo * 2 + 1) * 512 + row * 16 + cl0];
            float s0 = p0.x + p1.x, s1 = p0.y + p1.y, s2 = p0.z + p1.z, s3 = p0.w + p1.w;
            const float* xt = X + (size_t)t * Vv;
            float u0 = s0 + bbv.x, u1 = s1 + bbv.y, u2 = s2 + bbv.z, u3 = s3 + bbv.w;
            if (js < 8) {
                int j0 = js * 64 + c4;
                float x0 = xt[j0], x1 = xt[j0 + 1], x2 = xt[j0 + 2], x3 = xt[j0 + 3];
                if (i_glob != j0)     u0 = 0.5f * u0 + 0.5f * x0;
                if (i_glob != j0 + 1) u1 = 0.5f * u1 + 0.5f * x1;
                if (i_glob != j0 + 2) u2 = 0.5f * u2 + 0.5f * x2;
                if (i_glob != j0 + 3) u3 = 0.5f * u3 + 0.5f * x3;
            }
            u0 = fmaxf(u0, 0.f); u1 = fmaxf(u1, 0.f);
            u2 = fmaxf(u2, 0.f); u3 = fmaxf(u3, 0.f);
            u16 h0, m0, l0, h1, m1, l1, h2, m2, l2, h3, m3, l3;
            split3(u0, h0, m0, l0); split3(u1, h1, m1, l1);
            split3(u2, h2, m2, l2); split3(u3, h3, m3, l3);
            u64 ph = (u64)h0 | ((u64)h1 << 16) | ((u64)h2 << 32) | ((u64)h3 << 48);
            u64 pm = (u64)m0 | ((u64)m1 << 16) | ((u64)m2 << 32) | ((u64)m3 << 48);
            u64 pl = (u64)l0 | ((u64)l1 << 16) | ((u64)l2 << 32) | ((u64)l3 << 48);
            size_t tbo = (size_t)(ig * 16 + js) * 12288
                       + (size_t)((c4 >> 3) * 32 + row) * 16 + (c4 & 7) * 2;
            GST(dstA + tbo, ph);
            GST(dstA + tbo + 4096, pm);
            GST(dstA + tbo + 8192, pl);
        }
        asm volatile("s_waitcnt vmcnt(0)" ::: "memory");
        __syncthreads();   // all waves' coherent stores drained
        if (tid == 0)
            __hip_atomic_store(&flg[ig * 16 + js], (unsigned)t, __ATOMIC_RELAXED,
                               __HIP_MEMORY_SCOPE_AGENT);
    }
#undef GLDA3
#undef DSWR3
#undef DSRD7
#undef MFMA12
#undef CHUNK_MID
}

// Final: out[i] = dot(R126[i,:], W[i,:]) + b[i]; R126 in A0 tiles (h+m+l exact)
__global__ void diag_kernel(const char* __restrict__ ws, const float* __restrict__ W,
                            const float* __restrict__ b, float* __restrict__ out) {
    int i = blockIdx.x, lane = threadIdx.x;
    const char* A0 = ws + OFF_A0;
    float s = 0.f;
#pragma unroll
    for (int rep = 0; rep < 2; ++rep) {
        int ko = lane + rep * 64;                 // k-octet 0..127
        int js = ko >> 3, o = ko & 7;
        size_t tb = (size_t)((i >> 5) * 16 + js) * 12288
                  + (size_t)(o * 32 + (i & 31)) * 16;
        s16x8 vh = *(const s16x8*)(A0 + tb);
        s16x8 vm = *(const s16x8*)(A0 + tb + 4096);
        s16x8 vl = *(const s16x8*)(A0 + tb + 8192);
        const float* wr = W + (size_t)i * Ff + ko * 8;
#pragma unroll
        for (int e = 0; e < 8; ++e)
            s += (bf2f(vh[e]) + bf2f(vm[e]) + bf2f(vl[e])) * wr[e];
    }
#pragma unroll
    for (int off = 32; off > 0; off >>= 1) s += __shfl_down(s, off);
    if (lane == 0) out[i] = s + b[i];
}

extern "C" void kernel_launch(void* const* d_in, const int* in_sizes, int n_in,
                              void* d_out, int out_size, void* d_ws, size_t ws_size,
                              hipStream_t stream) {
    const float* X = (const float*)d_in[0];   // (128, 512)
    const float* W = (const float*)d_in[1];   // (1024, 1024)
    const float* b = (const float*)d_in[2];   // (1024,)
    float* out = (float*)d_out;
    char* ws = (char*)d_ws;

    hipFuncSetAttribute(reinterpret_cast<const void*>(mega_kernel),
                        hipFuncAttributeMaxDynamicSharedMemorySize, 155648);

    wsplit_kernel<<<512, 256, 0, stream>>>(W, ws);
    init_kernel<<<256, 256, 0, stream>>>(X, b, ws);
    mega_kernel<<<256, 512, 155648, stream>>>(X, b, ws);
    diag_kernel<<<512, 64, 0, stream>>>(ws, W, b, out);
}